// Round 3
// baseline (191.385 us; speedup 1.0000x reference)
//
#include <hip/hip_runtime.h>

#define D 128

// ---------------- Fallback phase 1: edge scatter with atomics ----------------
__global__ __launch_bounds__(256) void k_scatter(
    const float* __restrict__ h,
    const int* __restrict__ src,
    const int* __restrict__ dst,
    const float* __restrict__ mask,
    float* __restrict__ neigh,
    long long total)
{
    long long i = (long long)blockIdx.x * blockDim.x + threadIdx.x;
    if (i >= total) return;
    int e = (int)(i >> 7);
    int d = (int)(i & 127);
    int s = src[e];
    int t = dst[e];
    float m = mask[e];
    atomicAdd(&neigh[(long long)t * D + d], h[(long long)s * D + d] * m);
}

// ---------------- Sort by dst: histogram ----------------
__global__ __launch_bounds__(256) void k_hist(
    const int* __restrict__ dst, int* cnt, int E)
{
    int e = blockIdx.x * 256 + threadIdx.x;
    if (e < E) atomicAdd(&cnt[dst[e]], 1);
}

// ---------------- Scan phase A: per-block exclusive scan + block sums ----------------
__global__ __launch_bounds__(256) void k_scanA(
    const int* __restrict__ cnt, int* rowptr, int* bsum, int N)
{
    __shared__ int tmp[256];
    const int t = threadIdx.x;
    const int i = blockIdx.x * 256 + t;
    int v = (i < N) ? cnt[i] : 0;
    tmp[t] = v;
    __syncthreads();
#pragma unroll
    for (int off = 1; off < 256; off <<= 1) {
        int y = (t >= off) ? tmp[t - off] : 0;
        __syncthreads();
        tmp[t] += y;
        __syncthreads();
    }
    if (i < N) rowptr[i] = tmp[t] - v;   // exclusive within block
    if (t == 255) bsum[blockIdx.x] = tmp[255];
}

// ---------------- Scan phase B: scan the block sums (single block, chunked) ----------------
__global__ __launch_bounds__(256) void k_scanB(int* bsum, int NB)
{
    __shared__ int tmp[256];
    const int t = threadIdx.x;
    int carry = 0;
    for (int base = 0; base < NB; base += 256) {
        int i = base + t;
        int v = (i < NB) ? bsum[i] : 0;
        tmp[t] = v;
        __syncthreads();
#pragma unroll
        for (int off = 1; off < 256; off <<= 1) {
            int y = (t >= off) ? tmp[t - off] : 0;
            __syncthreads();
            tmp[t] += y;
            __syncthreads();
        }
        int inc = tmp[t];
        if (i < NB) bsum[i] = carry + inc - v;  // exclusive + carry
        carry += tmp[255];
        __syncthreads();
    }
}

// ---------------- Scan phase C: add block offsets, emit rowptr + cursor ----------------
__global__ __launch_bounds__(256) void k_scanC(
    int* rowptr, const int* __restrict__ bsum, int* cursor, int N, int E)
{
    int i = blockIdx.x * 256 + threadIdx.x;
    if (i < N) {
        int v = rowptr[i] + bsum[i >> 8];
        rowptr[i] = v;
        cursor[i] = v;
    }
    if (i == N) rowptr[N] = E;
}

// ---------------- Reorder edges into dst-sorted (src, mask) pairs ----------------
__global__ __launch_bounds__(256) void k_reorder(
    const int* __restrict__ src, const int* __restrict__ dst,
    const float* __restrict__ mask, int* cursor,
    int2* __restrict__ es, int E)
{
    int e = blockIdx.x * 256 + threadIdx.x;
    if (e < E) {
        int t = dst[e];
        int p = atomicAdd(&cursor[t], 1);
        es[p] = make_int2(src[e], __float_as_int(mask[e]));
    }
}

// ---------------- Fused gather + 2-layer MLP ----------------
// Per block: 32 nodes. Wave wv gathers nodes [wv*8, wv*8+8) into in_lds
// (hin = (1+eps)*h[n] + sum_e mask*h[src]); then both GEMM layers run with
// W chunks (32 rows, 16KB) software-pipelined through registers:
//   iteration t: compute chunk t (Wl), then barrier, ds_write prefetched
//   chunk t+1, issue global load of chunk t+2, barrier.
// Chunks 0..3 = W1, 4..7 = W2; ReLU->in_lds handoff spliced at t==3.
// Thread tile: 4 rows x 4 cols (cg=(tid&31)*4, rg=(tid>>5)*4).
// LDS = 16KB in + 16KB W = 32KB -> 5 blocks/CU.
__global__ __launch_bounds__(256) void k_fused(
    const float* __restrict__ h,
    const int* __restrict__ rowptr,
    const int2* __restrict__ es,
    const float* __restrict__ W1,
    const float* __restrict__ b1,
    const float* __restrict__ W2,
    const float* __restrict__ b2,
    const float* __restrict__ eps,
    const float* __restrict__ alpha,
    float* __restrict__ out,
    int N)
{
    __shared__ float in_lds[32][D];
    __shared__ float Wl[32][D];

    const int tid = threadIdx.x;
    const int lane = tid & 63;
    const int wv = tid >> 6;          // wave id 0..3
    const int cg = (tid & 31) * 4;    // output column group
    const int rg = (tid >> 5) * 4;    // output row group
    const int row0 = blockIdx.x * 32;

    // ---- prefetch W1 chunk 0 into registers (overlaps the gather) ----
    float4 wreg[4];
#pragma unroll
    for (int i = 0; i < 4; i++) {
        int p = i * 256 + tid;
        wreg[i] = *(const float4*)&W1[(p >> 5) * D + (p & 31) * 4];
    }

    // ---- gather phase: 8 nodes per wave, float2 per lane ----
    {
        const float s1 = 1.0f + eps[0];
        const int col = lane * 2;
        for (int s = 0; s < 8; s++) {
            int r = wv * 8 + s;
            int node = row0 + r;
            float ax = 0.0f, ay = 0.0f;
            if (node < N) {
                int jb = __builtin_amdgcn_readfirstlane(rowptr[node]);
                int je = __builtin_amdgcn_readfirstlane(rowptr[node + 1]);
                int j = jb;
                for (; j + 4 <= je; j += 4) {
                    int2 e0 = es[j];
                    int2 e1 = es[j + 1];
                    int2 e2 = es[j + 2];
                    int2 e3 = es[j + 3];
                    float2 v0 = *(const float2*)&h[(e0.x << 7) + col];
                    float2 v1 = *(const float2*)&h[(e1.x << 7) + col];
                    float2 v2 = *(const float2*)&h[(e2.x << 7) + col];
                    float2 v3 = *(const float2*)&h[(e3.x << 7) + col];
                    float m0 = __int_as_float(e0.y), m1 = __int_as_float(e1.y);
                    float m2 = __int_as_float(e2.y), m3 = __int_as_float(e3.y);
                    ax = fmaf(v0.x, m0, ax); ay = fmaf(v0.y, m0, ay);
                    ax = fmaf(v1.x, m1, ax); ay = fmaf(v1.y, m1, ay);
                    ax = fmaf(v2.x, m2, ax); ay = fmaf(v2.y, m2, ay);
                    ax = fmaf(v3.x, m3, ax); ay = fmaf(v3.y, m3, ay);
                }
                for (; j < je; ++j) {
                    int2 e0 = es[j];
                    float2 v0 = *(const float2*)&h[(e0.x << 7) + col];
                    float m0 = __int_as_float(e0.y);
                    ax = fmaf(v0.x, m0, ax); ay = fmaf(v0.y, m0, ay);
                }
                float2 hv = *(const float2*)&h[((long long)node << 7) + col];
                ax = fmaf(s1, hv.x, ax);
                ay = fmaf(s1, hv.y, ay);
            }
            float2 o = make_float2(ax, ay);
            *(float2*)&in_lds[r][col] = o;
        }
    }

    float4 acc[4];
#pragma unroll
    for (int r = 0; r < 4; r++) acc[r] = make_float4(0.f, 0.f, 0.f, 0.f);

    __syncthreads();   // gather (in_lds) complete across all waves

    // write W chunk 0, prefetch chunk 1
#pragma unroll
    for (int i = 0; i < 4; i++) {
        int p = i * 256 + tid;
        *(float4*)&Wl[p >> 5][(p & 31) * 4] = wreg[i];
    }
    {
        const float* Wsrc = W1 + 32 * D;
#pragma unroll
        for (int i = 0; i < 4; i++) {
            int p = i * 256 + tid;
            wreg[i] = *(const float4*)&Wsrc[(p >> 5) * D + (p & 31) * 4];
        }
    }
    __syncthreads();   // Wl chunk 0 visible

    for (int t = 0; t < 8; t++) {
        const int kb = (t & 3) * 32;
        // ---- compute chunk t ----
#pragma unroll
        for (int k4 = 0; k4 < 32; k4 += 4) {
            float4 w0 = *(const float4*)&Wl[k4 + 0][cg];
            float4 w1 = *(const float4*)&Wl[k4 + 1][cg];
            float4 w2 = *(const float4*)&Wl[k4 + 2][cg];
            float4 w3 = *(const float4*)&Wl[k4 + 3][cg];
#pragma unroll
            for (int r = 0; r < 4; r++) {
                float4 iv = *(const float4*)&in_lds[rg + r][kb + k4];
                acc[r].x = fmaf(iv.x, w0.x, acc[r].x);
                acc[r].y = fmaf(iv.x, w0.y, acc[r].y);
                acc[r].z = fmaf(iv.x, w0.z, acc[r].z);
                acc[r].w = fmaf(iv.x, w0.w, acc[r].w);
                acc[r].x = fmaf(iv.y, w1.x, acc[r].x);
                acc[r].y = fmaf(iv.y, w1.y, acc[r].y);
                acc[r].z = fmaf(iv.y, w1.z, acc[r].z);
                acc[r].w = fmaf(iv.y, w1.w, acc[r].w);
                acc[r].x = fmaf(iv.z, w2.x, acc[r].x);
                acc[r].y = fmaf(iv.z, w2.y, acc[r].y);
                acc[r].z = fmaf(iv.z, w2.z, acc[r].z);
                acc[r].w = fmaf(iv.z, w2.w, acc[r].w);
                acc[r].x = fmaf(iv.w, w3.x, acc[r].x);
                acc[r].y = fmaf(iv.w, w3.y, acc[r].y);
                acc[r].z = fmaf(iv.w, w3.z, acc[r].z);
                acc[r].w = fmaf(iv.w, w3.w, acc[r].w);
            }
        }

        if (t == 7) break;             // epilogue handles the store

        __syncthreads();               // all reads of Wl (and in_lds at t==3) done

        if (t == 3) {
            // layer-1 epilogue: relu(acc + b1) -> hidden into in_lds
            float4 bb = *(const float4*)&b1[cg];
#pragma unroll
            for (int r = 0; r < 4; r++) {
                float4 v;
                v.x = fmaxf(acc[r].x + bb.x, 0.0f);
                v.y = fmaxf(acc[r].y + bb.y, 0.0f);
                v.z = fmaxf(acc[r].z + bb.z, 0.0f);
                v.w = fmaxf(acc[r].w + bb.w, 0.0f);
                *(float4*)&in_lds[rg + r][cg] = v;
                acc[r] = make_float4(0.f, 0.f, 0.f, 0.f);
            }
        }

        // write prefetched chunk t+1 into Wl
#pragma unroll
        for (int i = 0; i < 4; i++) {
            int p = i * 256 + tid;
            *(float4*)&Wl[p >> 5][(p & 31) * 4] = wreg[i];
        }
        // issue global load of chunk t+2 (consumed next iteration)
        if (t < 6) {
            int nc = t + 2;
            const float* Wsrc = (nc < 4) ? (W1 + nc * 32 * D)
                                         : (W2 + (nc - 4) * 32 * D);
#pragma unroll
            for (int i = 0; i < 4; i++) {
                int p = i * 256 + tid;
                wreg[i] = *(const float4*)&Wsrc[(p >> 5) * D + (p & 31) * 4];
            }
        }
        __syncthreads();               // new Wl chunk (and hidden) visible
    }

    // ---- final epilogue: prelu(acc + b2) -> out ----
    {
        float4 bb = *(const float4*)&b2[cg];
        const float al = alpha[0];
#pragma unroll
        for (int r = 0; r < 4; r++) {
            int row = row0 + rg + r;
            if (row < N) {
                float4 v;
                v.x = acc[r].x + bb.x; v.x = (v.x >= 0.0f) ? v.x : al * v.x;
                v.y = acc[r].y + bb.y; v.y = (v.y >= 0.0f) ? v.y : al * v.y;
                v.z = acc[r].z + bb.z; v.z = (v.z >= 0.0f) ? v.z : al * v.z;
                v.w = acc[r].w + bb.w; v.w = (v.w >= 0.0f) ? v.w : al * v.w;
                *(float4*)&out[(long long)row * D + cg] = v;
            }
        }
    }
}

// ---------------- Fallback fused MLP (atomic-scatter path) ----------------
__device__ __forceinline__ void mlp_compute(
    const float in_lds[32][D], float Wl[32][D], const float* __restrict__ W,
    int tid, int cg, int rg, float4 acc[4])
{
    acc[0] = make_float4(0.f, 0.f, 0.f, 0.f);
    acc[1] = make_float4(0.f, 0.f, 0.f, 0.f);
    acc[2] = make_float4(0.f, 0.f, 0.f, 0.f);
    acc[3] = make_float4(0.f, 0.f, 0.f, 0.f);

    for (int kc = 0; kc < 4; kc++) {
        __syncthreads();
        for (int i = tid; i < 32 * (D / 4); i += 256) {
            int k = i >> 5;
            int cc = (i & 31) * 4;
            *(float4*)&Wl[k][cc] = *(const float4*)&W[(kc * 32 + k) * D + cc];
        }
        __syncthreads();

        const int kb = kc * 32;
#pragma unroll
        for (int k4 = 0; k4 < 32; k4 += 4) {
            float4 w0 = *(const float4*)&Wl[k4 + 0][cg];
            float4 w1 = *(const float4*)&Wl[k4 + 1][cg];
            float4 w2 = *(const float4*)&Wl[k4 + 2][cg];
            float4 w3 = *(const float4*)&Wl[k4 + 3][cg];
#pragma unroll
            for (int r = 0; r < 4; r++) {
                float4 iv = *(const float4*)&in_lds[rg + r][kb + k4];
                acc[r].x = fmaf(iv.x, w0.x, acc[r].x);
                acc[r].y = fmaf(iv.x, w0.y, acc[r].y);
                acc[r].z = fmaf(iv.x, w0.z, acc[r].z);
                acc[r].w = fmaf(iv.x, w0.w, acc[r].w);
                acc[r].x = fmaf(iv.y, w1.x, acc[r].x);
                acc[r].y = fmaf(iv.y, w1.y, acc[r].y);
                acc[r].z = fmaf(iv.y, w1.z, acc[r].z);
                acc[r].w = fmaf(iv.y, w1.w, acc[r].w);
                acc[r].x = fmaf(iv.z, w2.x, acc[r].x);
                acc[r].y = fmaf(iv.z, w2.y, acc[r].y);
                acc[r].z = fmaf(iv.z, w2.z, acc[r].z);
                acc[r].w = fmaf(iv.z, w2.w, acc[r].w);
                acc[r].x = fmaf(iv.w, w3.x, acc[r].x);
                acc[r].y = fmaf(iv.w, w3.y, acc[r].y);
                acc[r].z = fmaf(iv.w, w3.z, acc[r].z);
                acc[r].w = fmaf(iv.w, w3.w, acc[r].w);
            }
        }
    }
}

__global__ __launch_bounds__(256) void k_mlp2_fb(
    const float* __restrict__ A,
    const float* __restrict__ B,
    const float* __restrict__ W1,
    const float* __restrict__ b1,
    const float* __restrict__ W2,
    const float* __restrict__ b2,
    const float* __restrict__ eps,
    const float* __restrict__ alpha,
    float* __restrict__ out,
    int N)
{
    __shared__ float in_lds[32][D];
    __shared__ float Wl[32][D];

    const int tid = threadIdx.x;
    const int cg = (tid & 31) * 4;
    const int rg = (tid >> 5) * 4;
    const int row0 = blockIdx.x * 32;

    {
        const float s1 = 1.0f + eps[0];
        for (int i = tid; i < 32 * (D / 4); i += 256) {
            int r = i >> 5;
            int cc = (i & 31) * 4;
            float4 v = make_float4(0.f, 0.f, 0.f, 0.f);
            if (row0 + r < N) {
                float4 a = *(const float4*)&A[(long long)(row0 + r) * D + cc];
                float4 b4 = *(const float4*)&B[(long long)(row0 + r) * D + cc];
                v.x = fmaf(s1, a.x, b4.x);
                v.y = fmaf(s1, a.y, b4.y);
                v.z = fmaf(s1, a.z, b4.z);
                v.w = fmaf(s1, a.w, b4.w);
            }
            *(float4*)&in_lds[r][cc] = v;
        }
    }

    float4 acc[4];
    mlp_compute(in_lds, Wl, W1, tid, cg, rg, acc);

    __syncthreads();
    {
        float4 bb = *(const float4*)&b1[cg];
#pragma unroll
        for (int r = 0; r < 4; r++) {
            float4 v;
            v.x = fmaxf(acc[r].x + bb.x, 0.0f);
            v.y = fmaxf(acc[r].y + bb.y, 0.0f);
            v.z = fmaxf(acc[r].z + bb.z, 0.0f);
            v.w = fmaxf(acc[r].w + bb.w, 0.0f);
            *(float4*)&in_lds[rg + r][cg] = v;
        }
    }

    mlp_compute(in_lds, Wl, W2, tid, cg, rg, acc);

    {
        float4 bb = *(const float4*)&b2[cg];
        const float al = alpha[0];
#pragma unroll
        for (int r = 0; r < 4; r++) {
            int row = row0 + rg + r;
            if (row < N) {
                float4 v;
                v.x = acc[r].x + bb.x; v.x = (v.x >= 0.0f) ? v.x : al * v.x;
                v.y = acc[r].y + bb.y; v.y = (v.y >= 0.0f) ? v.y : al * v.y;
                v.z = acc[r].z + bb.z; v.z = (v.z >= 0.0f) ? v.z : al * v.z;
                v.w = acc[r].w + bb.w; v.w = (v.w >= 0.0f) ? v.w : al * v.w;
                *(float4*)&out[(long long)row * D + cg] = v;
            }
        }
    }
}

extern "C" void kernel_launch(void* const* d_in, const int* in_sizes, int n_in,
                              void* d_out, int out_size, void* d_ws, size_t ws_size,
                              hipStream_t stream)
{
    const float* h     = (const float*)d_in[0];
    // d_in[1] = snorm_n (unused by reference)
    const int*   src   = (const int*)d_in[2];
    const int*   dst   = (const int*)d_in[3];
    const float* mask  = (const float*)d_in[4];
    const float* eps   = (const float*)d_in[5];
    const float* W1    = (const float*)d_in[6];
    const float* b1    = (const float*)d_in[7];
    const float* W2    = (const float*)d_in[8];
    const float* b2    = (const float*)d_in[9];
    const float* alpha = (const float*)d_in[10];

    const int N = in_sizes[0] / D;
    const int E = in_sizes[2];
    float* out = (float*)d_out;

    const int mblocks = (N + 31) / 32;
    const int NB = (N + 255) / 256;  // scan blocks

    // Workspace layout (256B aligned)
    char* base = (char*)d_ws;
    size_t offEs  = 0;
    size_t offRp  = (offEs + (size_t)E * 8 + 255) & ~(size_t)255;
    size_t offCnt = (offRp + (size_t)(N + 1) * 4 + 255) & ~(size_t)255;
    size_t offCur = (offCnt + (size_t)N * 4 + 255) & ~(size_t)255;
    size_t offBs  = (offCur + (size_t)N * 4 + 255) & ~(size_t)255;
    size_t need   = offBs + (size_t)NB * 4;

    if (ws_size >= need) {
        // ---------- sorted-gather path (no fp32 atomics) ----------
        int2*  es     = (int2*)(base + offEs);
        int*   rowptr = (int*)(base + offRp);
        int*   cnt    = (int*)(base + offCnt);
        int*   cursor = (int*)(base + offCur);
        int*   bsum   = (int*)(base + offBs);

        hipMemsetAsync(cnt, 0, (size_t)N * 4, stream);

        int eblocks = (E + 255) / 256;
        k_hist<<<eblocks, 256, 0, stream>>>(dst, cnt, E);
        k_scanA<<<NB, 256, 0, stream>>>(cnt, rowptr, bsum, N);
        k_scanB<<<1, 256, 0, stream>>>(bsum, NB);
        k_scanC<<<(N + 1 + 255) / 256, 256, 0, stream>>>(rowptr, bsum, cursor, N, E);
        k_reorder<<<eblocks, 256, 0, stream>>>(src, dst, mask, cursor, es, E);

        k_fused<<<mblocks, 256, 0, stream>>>(h, rowptr, es, W1, b1, W2, b2,
                                             eps, alpha, out, N);
    } else {
        // ---------- fallback: atomic-scatter path ----------
        float* neigh = (float*)d_ws;
        hipMemsetAsync(neigh, 0, (size_t)N * D * sizeof(float), stream);
        long long total = (long long)E * D;
        int blocks = (int)((total + 255) / 256);
        k_scatter<<<blocks, 256, 0, stream>>>(h, src, dst, mask, neigh, total);
        k_mlp2_fb<<<mblocks, 256, 0, stream>>>(h, neigh, W1, b1, W2, b2,
                                               eps, alpha, out, N);
    }
}

// Round 4
// 174.985 us; speedup vs baseline: 1.0937x; 1.0937x over previous
//
#include <hip/hip_runtime.h>

#define D 128

// ---------------- Fallback phase 1: edge scatter with atomics ----------------
__global__ __launch_bounds__(256) void k_scatter(
    const float* __restrict__ h,
    const int* __restrict__ src,
    const int* __restrict__ dst,
    const float* __restrict__ mask,
    float* __restrict__ neigh,
    long long total)
{
    long long i = (long long)blockIdx.x * blockDim.x + threadIdx.x;
    if (i >= total) return;
    int e = (int)(i >> 7);
    int d = (int)(i & 127);
    int s = src[e];
    int t = dst[e];
    float m = mask[e];
    atomicAdd(&neigh[(long long)t * D + d], h[(long long)s * D + d] * m);
}

// ---------------- Sort by dst: histogram ----------------
__global__ __launch_bounds__(256) void k_hist(
    const int* __restrict__ dst, int* cnt, int E)
{
    int e = blockIdx.x * 256 + threadIdx.x;
    if (e < E) atomicAdd(&cnt[dst[e]], 1);
}

// ---------------- Scan phase A: per-block exclusive scan + raw block sums ----------------
__global__ __launch_bounds__(256) void k_scanA(
    const int* __restrict__ cnt, int* rowptr, int* bsum, int N)
{
    __shared__ int tmp[256];
    const int t = threadIdx.x;
    const int i = blockIdx.x * 256 + t;
    int v = (i < N) ? cnt[i] : 0;
    tmp[t] = v;
    __syncthreads();
#pragma unroll
    for (int off = 1; off < 256; off <<= 1) {
        int y = (t >= off) ? tmp[t - off] : 0;
        __syncthreads();
        tmp[t] += y;
        __syncthreads();
    }
    if (i < N) rowptr[i] = tmp[t] - v;   // exclusive within block
    if (t == 255) bsum[blockIdx.x] = tmp[255];   // raw block total
}

// ---------------- Scan phase C: per-block reduce of bsum prefix + emit ----------------
// Each block reduces bsum[0 .. blockIdx.x-1] itself (NB is small), removing
// the separate single-block scan launch.
__global__ __launch_bounds__(256) void k_scanC2(
    int* rowptr, const int* __restrict__ bsum, int* cursor, int N, int E, int NB)
{
    __shared__ int red[256];
    const int t = threadIdx.x;
    const int b = blockIdx.x;
    int partial = 0;
    int lim = (b < NB) ? b : NB;
    for (int base = 0; base < lim; base += 256) {
        int idx = base + t;
        if (idx < lim) partial += bsum[idx];
    }
    red[t] = partial;
    __syncthreads();
#pragma unroll
    for (int off = 128; off > 0; off >>= 1) {
        if (t < off) red[t] += red[t + off];
        __syncthreads();
    }
    const int boff = red[0];
    int i = b * 256 + t;
    if (i < N) {
        int v = rowptr[i] + boff;
        rowptr[i] = v;
        cursor[i] = v;
    }
    if (i == N) rowptr[N] = E;
}

// ---------------- Reorder edges into dst-sorted (src, mask) pairs ----------------
__global__ __launch_bounds__(256) void k_reorder(
    const int* __restrict__ src, const int* __restrict__ dst,
    const float* __restrict__ mask, int* cursor,
    int2* __restrict__ es, int E)
{
    int e = blockIdx.x * 256 + threadIdx.x;
    if (e < E) {
        int t = dst[e];
        int p = atomicAdd(&cursor[t], 1);
        es[p] = make_int2(src[e], __float_as_int(mask[e]));
    }
}

// ---------------- Gather-aggregate: one wave per node, 2 edges in flight ----------------
// Lanes 0-31 accumulate even-indexed edges, lanes 32-63 odd-indexed; each lane
// holds float4 (16B) of the 512B row -> one wave load covers 2 edges.
// hin[n] = (1+eps)*h[n] + sum_{e: dst=n} h[src_e] * mask_e
__global__ __launch_bounds__(256) void k_gather(
    const float* __restrict__ h,
    const int* __restrict__ rowptr,
    const int2* __restrict__ es,
    const float* __restrict__ eps,
    float* __restrict__ hin, int N)
{
    int wid = blockIdx.x * 4 + (threadIdx.x >> 6);   // node (one wave each)
    if (wid >= N) return;
    const int lane = threadIdx.x & 63;
    const int half = lane >> 5;
    const int col4 = (lane & 31) * 4;

    int jb = __builtin_amdgcn_readfirstlane(rowptr[wid]);
    int je = __builtin_amdgcn_readfirstlane(rowptr[wid + 1]);

    float4 a = make_float4(0.f, 0.f, 0.f, 0.f);
    int j = jb;
    // 8 edges per iteration (4 per half-wave)
    for (; j + 8 <= je; j += 8) {
#pragma unroll
        for (int u = 0; u < 4; u++) {
            int2 e = es[j + 2 * u + half];
            float4 v = *(const float4*)&h[((long long)e.x << 7) + col4];
            float m = __int_as_float(e.y);
            a.x = fmaf(v.x, m, a.x);
            a.y = fmaf(v.y, m, a.y);
            a.z = fmaf(v.z, m, a.z);
            a.w = fmaf(v.w, m, a.w);
        }
    }
    // 2 edges per iteration
    for (; j + 2 <= je; j += 2) {
        int2 e = es[j + half];
        float4 v = *(const float4*)&h[((long long)e.x << 7) + col4];
        float m = __int_as_float(e.y);
        a.x = fmaf(v.x, m, a.x);
        a.y = fmaf(v.y, m, a.y);
        a.z = fmaf(v.z, m, a.z);
        a.w = fmaf(v.w, m, a.w);
    }
    // odd leftover edge: half 0 only
    if (j < je && half == 0) {
        int2 e = es[j];
        float4 v = *(const float4*)&h[((long long)e.x << 7) + col4];
        float m = __int_as_float(e.y);
        a.x = fmaf(v.x, m, a.x);
        a.y = fmaf(v.y, m, a.y);
        a.z = fmaf(v.z, m, a.z);
        a.w = fmaf(v.w, m, a.w);
    }

    // combine halves (lane ^ 32)
    a.x += __shfl_xor(a.x, 32, 64);
    a.y += __shfl_xor(a.y, 32, 64);
    a.z += __shfl_xor(a.z, 32, 64);
    a.w += __shfl_xor(a.w, 32, 64);

    float4 hv = *(const float4*)&h[((long long)wid << 7) + col4];
    const float s1 = 1.0f + eps[0];
    float4 o;
    o.x = fmaf(s1, hv.x, a.x);
    o.y = fmaf(s1, hv.y, a.y);
    o.z = fmaf(s1, hv.z, a.z);
    o.w = fmaf(s1, hv.w, a.w);
    if (half == 0)
        *(float4*)&hin[((long long)wid << 7) + col4] = o;
}

// ---------------- Fused 2-layer MLP, W software-pipelined through registers ----
// out = prelu_alpha( relu(in @ W1 + b1) @ W2 + b2 ),  in = hin (pre-combined).
// 256 threads, 32 rows/block, thread tile 4 rows x 4 cols.
// W chunks (32 rows, 16KB): chunk t+2 global-loaded into VGPRs during compute
// of chunk t; only ds_write + barrier between compute phases.
// Chunks 0..3 = W1, 4..7 = W2; ReLU handoff spliced at t==3.
// LDS = 16KB in + 16KB W = 32KB -> 5 blocks/CU.
__global__ __launch_bounds__(256) void k_mlp2p(
    const float* __restrict__ hin,
    const float* __restrict__ W1,
    const float* __restrict__ b1,
    const float* __restrict__ W2,
    const float* __restrict__ b2,
    const float* __restrict__ alpha,
    float* __restrict__ out,
    int N)
{
    __shared__ float in_lds[32][D];
    __shared__ float Wl[32][D];

    const int tid = threadIdx.x;
    const int cg = (tid & 31) * 4;
    const int rg = (tid >> 5) * 4;
    const int row0 = blockIdx.x * 32;

    // prefetch W1 chunk 0 into registers
    float4 wreg[4];
#pragma unroll
    for (int i = 0; i < 4; i++) {
        int p = i * 256 + tid;
        wreg[i] = *(const float4*)&W1[(p >> 5) * D + (p & 31) * 4];
    }

    // stage 32 input rows (independent loads, overlap the W prefetch)
#pragma unroll
    for (int i = 0; i < 4; i++) {
        int p = i * 256 + tid;
        int r = p >> 5;
        int cc = (p & 31) * 4;
        float4 v = make_float4(0.f, 0.f, 0.f, 0.f);
        if (row0 + r < N)
            v = *(const float4*)&hin[(long long)(row0 + r) * D + cc];
        *(float4*)&in_lds[r][cc] = v;
    }

    // write W chunk 0 into LDS, prefetch chunk 1
#pragma unroll
    for (int i = 0; i < 4; i++) {
        int p = i * 256 + tid;
        *(float4*)&Wl[p >> 5][(p & 31) * 4] = wreg[i];
    }
    {
        const float* Wsrc = W1 + 32 * D;
#pragma unroll
        for (int i = 0; i < 4; i++) {
            int p = i * 256 + tid;
            wreg[i] = *(const float4*)&Wsrc[(p >> 5) * D + (p & 31) * 4];
        }
    }

    float4 acc[4];
#pragma unroll
    for (int r = 0; r < 4; r++) acc[r] = make_float4(0.f, 0.f, 0.f, 0.f);

    __syncthreads();   // in_lds + Wl chunk 0 visible

    for (int t = 0; t < 8; t++) {
        const int kb = (t & 3) * 32;
#pragma unroll
        for (int k4 = 0; k4 < 32; k4 += 4) {
            float4 w0 = *(const float4*)&Wl[k4 + 0][cg];
            float4 w1 = *(const float4*)&Wl[k4 + 1][cg];
            float4 w2 = *(const float4*)&Wl[k4 + 2][cg];
            float4 w3 = *(const float4*)&Wl[k4 + 3][cg];
#pragma unroll
            for (int r = 0; r < 4; r++) {
                float4 iv = *(const float4*)&in_lds[rg + r][kb + k4];
                acc[r].x = fmaf(iv.x, w0.x, acc[r].x);
                acc[r].y = fmaf(iv.x, w0.y, acc[r].y);
                acc[r].z = fmaf(iv.x, w0.z, acc[r].z);
                acc[r].w = fmaf(iv.x, w0.w, acc[r].w);
                acc[r].x = fmaf(iv.y, w1.x, acc[r].x);
                acc[r].y = fmaf(iv.y, w1.y, acc[r].y);
                acc[r].z = fmaf(iv.y, w1.z, acc[r].z);
                acc[r].w = fmaf(iv.y, w1.w, acc[r].w);
                acc[r].x = fmaf(iv.z, w2.x, acc[r].x);
                acc[r].y = fmaf(iv.z, w2.y, acc[r].y);
                acc[r].z = fmaf(iv.z, w2.z, acc[r].z);
                acc[r].w = fmaf(iv.z, w2.w, acc[r].w);
                acc[r].x = fmaf(iv.w, w3.x, acc[r].x);
                acc[r].y = fmaf(iv.w, w3.y, acc[r].y);
                acc[r].z = fmaf(iv.w, w3.z, acc[r].z);
                acc[r].w = fmaf(iv.w, w3.w, acc[r].w);
            }
        }

        if (t == 7) break;

        __syncthreads();   // all reads of Wl (and in_lds at t==3) done

        if (t == 3) {
            // layer-1 epilogue: relu(acc + b1) -> hidden into in_lds
            float4 bb = *(const float4*)&b1[cg];
#pragma unroll
            for (int r = 0; r < 4; r++) {
                float4 v;
                v.x = fmaxf(acc[r].x + bb.x, 0.0f);
                v.y = fmaxf(acc[r].y + bb.y, 0.0f);
                v.z = fmaxf(acc[r].z + bb.z, 0.0f);
                v.w = fmaxf(acc[r].w + bb.w, 0.0f);
                *(float4*)&in_lds[rg + r][cg] = v;
                acc[r] = make_float4(0.f, 0.f, 0.f, 0.f);
            }
        }

        // write prefetched chunk t+1
#pragma unroll
        for (int i = 0; i < 4; i++) {
            int p = i * 256 + tid;
            *(float4*)&Wl[p >> 5][(p & 31) * 4] = wreg[i];
        }
        // issue global load of chunk t+2
        if (t < 6) {
            int nc = t + 2;
            const float* Wsrc = (nc < 4) ? (W1 + nc * 32 * D)
                                         : (W2 + (nc - 4) * 32 * D);
#pragma unroll
            for (int i = 0; i < 4; i++) {
                int p = i * 256 + tid;
                wreg[i] = *(const float4*)&Wsrc[(p >> 5) * D + (p & 31) * 4];
            }
        }
        __syncthreads();   // new Wl chunk (and hidden) visible
    }

    // final epilogue: prelu(acc + b2) -> out
    {
        float4 bb = *(const float4*)&b2[cg];
        const float al = alpha[0];
#pragma unroll
        for (int r = 0; r < 4; r++) {
            int row = row0 + rg + r;
            if (row < N) {
                float4 v;
                v.x = acc[r].x + bb.x; v.x = (v.x >= 0.0f) ? v.x : al * v.x;
                v.y = acc[r].y + bb.y; v.y = (v.y >= 0.0f) ? v.y : al * v.y;
                v.z = acc[r].z + bb.z; v.z = (v.z >= 0.0f) ? v.z : al * v.z;
                v.w = acc[r].w + bb.w; v.w = (v.w >= 0.0f) ? v.w : al * v.w;
                *(float4*)&out[(long long)row * D + cg] = v;
            }
        }
    }
}

// ---------------- Fallback fused MLP (atomic-scatter path) ----------------
__device__ __forceinline__ void mlp_compute(
    const float in_lds[32][D], float Wl[32][D], const float* __restrict__ W,
    int tid, int cg, int rg, float4 acc[4])
{
    acc[0] = make_float4(0.f, 0.f, 0.f, 0.f);
    acc[1] = make_float4(0.f, 0.f, 0.f, 0.f);
    acc[2] = make_float4(0.f, 0.f, 0.f, 0.f);
    acc[3] = make_float4(0.f, 0.f, 0.f, 0.f);

    for (int kc = 0; kc < 4; kc++) {
        __syncthreads();
        for (int i = tid; i < 32 * (D / 4); i += 256) {
            int k = i >> 5;
            int cc = (i & 31) * 4;
            *(float4*)&Wl[k][cc] = *(const float4*)&W[(kc * 32 + k) * D + cc];
        }
        __syncthreads();

        const int kb = kc * 32;
#pragma unroll
        for (int k4 = 0; k4 < 32; k4 += 4) {
            float4 w0 = *(const float4*)&Wl[k4 + 0][cg];
            float4 w1 = *(const float4*)&Wl[k4 + 1][cg];
            float4 w2 = *(const float4*)&Wl[k4 + 2][cg];
            float4 w3 = *(const float4*)&Wl[k4 + 3][cg];
#pragma unroll
            for (int r = 0; r < 4; r++) {
                float4 iv = *(const float4*)&in_lds[rg + r][kb + k4];
                acc[r].x = fmaf(iv.x, w0.x, acc[r].x);
                acc[r].y = fmaf(iv.x, w0.y, acc[r].y);
                acc[r].z = fmaf(iv.x, w0.z, acc[r].z);
                acc[r].w = fmaf(iv.x, w0.w, acc[r].w);
                acc[r].x = fmaf(iv.y, w1.x, acc[r].x);
                acc[r].y = fmaf(iv.y, w1.y, acc[r].y);
                acc[r].z = fmaf(iv.y, w1.z, acc[r].z);
                acc[r].w = fmaf(iv.y, w1.w, acc[r].w);
                acc[r].x = fmaf(iv.z, w2.x, acc[r].x);
                acc[r].y = fmaf(iv.z, w2.y, acc[r].y);
                acc[r].z = fmaf(iv.z, w2.z, acc[r].z);
                acc[r].w = fmaf(iv.z, w2.w, acc[r].w);
                acc[r].x = fmaf(iv.w, w3.x, acc[r].x);
                acc[r].y = fmaf(iv.w, w3.y, acc[r].y);
                acc[r].z = fmaf(iv.w, w3.z, acc[r].z);
                acc[r].w = fmaf(iv.w, w3.w, acc[r].w);
            }
        }
    }
}

__global__ __launch_bounds__(256) void k_mlp2_fb(
    const float* __restrict__ A,
    const float* __restrict__ B,
    const float* __restrict__ W1,
    const float* __restrict__ b1,
    const float* __restrict__ W2,
    const float* __restrict__ b2,
    const float* __restrict__ eps,
    const float* __restrict__ alpha,
    float* __restrict__ out,
    int N)
{
    __shared__ float in_lds[32][D];
    __shared__ float Wl[32][D];

    const int tid = threadIdx.x;
    const int cg = (tid & 31) * 4;
    const int rg = (tid >> 5) * 4;
    const int row0 = blockIdx.x * 32;

    {
        const float s1 = 1.0f + eps[0];
        for (int i = tid; i < 32 * (D / 4); i += 256) {
            int r = i >> 5;
            int cc = (i & 31) * 4;
            float4 v = make_float4(0.f, 0.f, 0.f, 0.f);
            if (row0 + r < N) {
                float4 a = *(const float4*)&A[(long long)(row0 + r) * D + cc];
                float4 b4 = *(const float4*)&B[(long long)(row0 + r) * D + cc];
                v.x = fmaf(s1, a.x, b4.x);
                v.y = fmaf(s1, a.y, b4.y);
                v.z = fmaf(s1, a.z, b4.z);
                v.w = fmaf(s1, a.w, b4.w);
            }
            *(float4*)&in_lds[r][cc] = v;
        }
    }

    float4 acc[4];
    mlp_compute(in_lds, Wl, W1, tid, cg, rg, acc);

    __syncthreads();
    {
        float4 bb = *(const float4*)&b1[cg];
#pragma unroll
        for (int r = 0; r < 4; r++) {
            float4 v;
            v.x = fmaxf(acc[r].x + bb.x, 0.0f);
            v.y = fmaxf(acc[r].y + bb.y, 0.0f);
            v.z = fmaxf(acc[r].z + bb.z, 0.0f);
            v.w = fmaxf(acc[r].w + bb.w, 0.0f);
            *(float4*)&in_lds[rg + r][cg] = v;
        }
    }

    mlp_compute(in_lds, Wl, W2, tid, cg, rg, acc);

    {
        float4 bb = *(const float4*)&b2[cg];
        const float al = alpha[0];
#pragma unroll
        for (int r = 0; r < 4; r++) {
            int row = row0 + rg + r;
            if (row < N) {
                float4 v;
                v.x = acc[r].x + bb.x; v.x = (v.x >= 0.0f) ? v.x : al * v.x;
                v.y = acc[r].y + bb.y; v.y = (v.y >= 0.0f) ? v.y : al * v.y;
                v.z = acc[r].z + bb.z; v.z = (v.z >= 0.0f) ? v.z : al * v.z;
                v.w = acc[r].w + bb.w; v.w = (v.w >= 0.0f) ? v.w : al * v.w;
                *(float4*)&out[(long long)row * D + cg] = v;
            }
        }
    }
}

extern "C" void kernel_launch(void* const* d_in, const int* in_sizes, int n_in,
                              void* d_out, int out_size, void* d_ws, size_t ws_size,
                              hipStream_t stream)
{
    const float* h     = (const float*)d_in[0];
    // d_in[1] = snorm_n (unused by reference)
    const int*   src   = (const int*)d_in[2];
    const int*   dst   = (const int*)d_in[3];
    const float* mask  = (const float*)d_in[4];
    const float* eps   = (const float*)d_in[5];
    const float* W1    = (const float*)d_in[6];
    const float* b1    = (const float*)d_in[7];
    const float* W2    = (const float*)d_in[8];
    const float* b2    = (const float*)d_in[9];
    const float* alpha = (const float*)d_in[10];

    const int N = in_sizes[0] / D;
    const int E = in_sizes[2];
    float* out = (float*)d_out;

    const int mblocks = (N + 31) / 32;
    const int NB = (N + 255) / 256;  // scan blocks

    // Workspace layout (256B aligned)
    char* base = (char*)d_ws;
    size_t offHin = 0;
    size_t offEs  = (offHin + (size_t)N * D * 4 + 255) & ~(size_t)255;
    size_t offRp  = (offEs + (size_t)E * 8 + 255) & ~(size_t)255;
    size_t offCnt = (offRp + (size_t)(N + 1) * 4 + 255) & ~(size_t)255;
    size_t offCur = (offCnt + (size_t)N * 4 + 255) & ~(size_t)255;
    size_t offBs  = (offCur + (size_t)N * 4 + 255) & ~(size_t)255;
    size_t need   = offBs + (size_t)NB * 4;

    if (ws_size >= need) {
        // ---------- sorted-gather path (no fp32 atomics) ----------
        float* hin    = (float*)(base + offHin);
        int2*  es     = (int2*)(base + offEs);
        int*   rowptr = (int*)(base + offRp);
        int*   cnt    = (int*)(base + offCnt);
        int*   cursor = (int*)(base + offCur);
        int*   bsum   = (int*)(base + offBs);

        hipMemsetAsync(cnt, 0, (size_t)N * 4, stream);

        int eblocks = (E + 255) / 256;
        k_hist<<<eblocks, 256, 0, stream>>>(dst, cnt, E);
        k_scanA<<<NB, 256, 0, stream>>>(cnt, rowptr, bsum, N);
        k_scanC2<<<(N + 1 + 255) / 256, 256, 0, stream>>>(rowptr, bsum, cursor,
                                                          N, E, NB);
        k_reorder<<<eblocks, 256, 0, stream>>>(src, dst, mask, cursor, es, E);
        k_gather<<<(N + 3) / 4, 256, 0, stream>>>(h, rowptr, es, eps, hin, N);

        k_mlp2p<<<mblocks, 256, 0, stream>>>(hin, W1, b1, W2, b2, alpha, out, N);
    } else {
        // ---------- fallback: atomic-scatter path ----------
        float* neigh = (float*)d_ws;
        hipMemsetAsync(neigh, 0, (size_t)N * D * sizeof(float), stream);
        long long total = (long long)E * D;
        int blocks = (int)((total + 255) / 256);
        k_scatter<<<blocks, 256, 0, stream>>>(h, src, dst, mask, neigh, total);
        k_mlp2_fb<<<mblocks, 256, 0, stream>>>(h, neigh, W1, b1, W2, b2,
                                               eps, alpha, out, N);
    }
}

// Round 5
// 145.839 us; speedup vs baseline: 1.3123x; 1.1998x over previous
//
#include <hip/hip_runtime.h>

#define D 128

typedef __attribute__((ext_vector_type(8))) short bf16x8;
typedef __attribute__((ext_vector_type(4))) float f32x4;

__device__ __forceinline__ unsigned short f2bf(float x) {
    unsigned u = __float_as_uint(x);
    return (unsigned short)((u + 0x7FFFu + ((u >> 16) & 1u)) >> 16);
}
__device__ __forceinline__ float bf2f(unsigned short b) {
    return __uint_as_float(((unsigned)b) << 16);
}

// ---------------- Fallback phase 1: edge scatter with atomics ----------------
__global__ __launch_bounds__(256) void k_scatter(
    const float* __restrict__ h,
    const int* __restrict__ src,
    const int* __restrict__ dst,
    const float* __restrict__ mask,
    float* __restrict__ neigh,
    long long total)
{
    long long i = (long long)blockIdx.x * blockDim.x + threadIdx.x;
    if (i >= total) return;
    int e = (int)(i >> 7);
    int d = (int)(i & 127);
    int s = src[e];
    int t = dst[e];
    float m = mask[e];
    atomicAdd(&neigh[(long long)t * D + d], h[(long long)s * D + d] * m);
}

// ---------------- Sort by dst: histogram ----------------
__global__ __launch_bounds__(256) void k_hist(
    const int* __restrict__ dst, int* cnt, int E)
{
    int e = blockIdx.x * 256 + threadIdx.x;
    if (e < E) atomicAdd(&cnt[dst[e]], 1);
}

// ---------------- Scan phase A: per-block exclusive scan + raw block sums ----------------
__global__ __launch_bounds__(256) void k_scanA(
    const int* __restrict__ cnt, int* rowptr, int* bsum, int N)
{
    __shared__ int tmp[256];
    const int t = threadIdx.x;
    const int i = blockIdx.x * 256 + t;
    int v = (i < N) ? cnt[i] : 0;
    tmp[t] = v;
    __syncthreads();
#pragma unroll
    for (int off = 1; off < 256; off <<= 1) {
        int y = (t >= off) ? tmp[t - off] : 0;
        __syncthreads();
        tmp[t] += y;
        __syncthreads();
    }
    if (i < N) rowptr[i] = tmp[t] - v;   // exclusive within block
    if (t == 255) bsum[blockIdx.x] = tmp[255];   // raw block total
}

// ---------------- Scan phase C: per-block reduce of bsum prefix + emit ----------------
__global__ __launch_bounds__(256) void k_scanC2(
    int* rowptr, const int* __restrict__ bsum, int* cursor, int N, int E, int NB)
{
    __shared__ int red[256];
    const int t = threadIdx.x;
    const int b = blockIdx.x;
    int partial = 0;
    int lim = (b < NB) ? b : NB;
    for (int base = 0; base < lim; base += 256) {
        int idx = base + t;
        if (idx < lim) partial += bsum[idx];
    }
    red[t] = partial;
    __syncthreads();
#pragma unroll
    for (int off = 128; off > 0; off >>= 1) {
        if (t < off) red[t] += red[t + off];
        __syncthreads();
    }
    const int boff = red[0];
    int i = b * 256 + t;
    if (i < N) {
        int v = rowptr[i] + boff;
        rowptr[i] = v;
        cursor[i] = v;
    }
    if (i == N) rowptr[N] = E;
}

// ---------------- Reorder edges into dst-sorted (src, mask) pairs ----------------
__global__ __launch_bounds__(256) void k_reorder(
    const int* __restrict__ src, const int* __restrict__ dst,
    const float* __restrict__ mask, int* cursor,
    int2* __restrict__ es, int E)
{
    int e = blockIdx.x * 256 + threadIdx.x;
    if (e < E) {
        int t = dst[e];
        int p = atomicAdd(&cursor[t], 1);
        es[p] = make_int2(src[e], __float_as_int(mask[e]));
    }
}

// ---------------- Gather-aggregate: one wave per node, 2 edges in flight ----------------
__global__ __launch_bounds__(256) void k_gather(
    const float* __restrict__ h,
    const int* __restrict__ rowptr,
    const int2* __restrict__ es,
    const float* __restrict__ eps,
    float* __restrict__ hin, int N)
{
    int wid = blockIdx.x * 4 + (threadIdx.x >> 6);   // node (one wave each)
    if (wid >= N) return;
    const int lane = threadIdx.x & 63;
    const int half = lane >> 5;
    const int col4 = (lane & 31) * 4;

    int jb = __builtin_amdgcn_readfirstlane(rowptr[wid]);
    int je = __builtin_amdgcn_readfirstlane(rowptr[wid + 1]);

    float4 a = make_float4(0.f, 0.f, 0.f, 0.f);
    int j = jb;
    for (; j + 8 <= je; j += 8) {
#pragma unroll
        for (int u = 0; u < 4; u++) {
            int2 e = es[j + 2 * u + half];
            float4 v = *(const float4*)&h[((long long)e.x << 7) + col4];
            float m = __int_as_float(e.y);
            a.x = fmaf(v.x, m, a.x);
            a.y = fmaf(v.y, m, a.y);
            a.z = fmaf(v.z, m, a.z);
            a.w = fmaf(v.w, m, a.w);
        }
    }
    for (; j + 2 <= je; j += 2) {
        int2 e = es[j + half];
        float4 v = *(const float4*)&h[((long long)e.x << 7) + col4];
        float m = __int_as_float(e.y);
        a.x = fmaf(v.x, m, a.x);
        a.y = fmaf(v.y, m, a.y);
        a.z = fmaf(v.z, m, a.z);
        a.w = fmaf(v.w, m, a.w);
    }
    if (j < je && half == 0) {
        int2 e = es[j];
        float4 v = *(const float4*)&h[((long long)e.x << 7) + col4];
        float m = __int_as_float(e.y);
        a.x = fmaf(v.x, m, a.x);
        a.y = fmaf(v.y, m, a.y);
        a.z = fmaf(v.z, m, a.z);
        a.w = fmaf(v.w, m, a.w);
    }

    a.x += __shfl_xor(a.x, 32, 64);
    a.y += __shfl_xor(a.y, 32, 64);
    a.z += __shfl_xor(a.z, 32, 64);
    a.w += __shfl_xor(a.w, 32, 64);

    float4 hv = *(const float4*)&h[((long long)wid << 7) + col4];
    const float s1 = 1.0f + eps[0];
    float4 o;
    o.x = fmaf(s1, hv.x, a.x);
    o.y = fmaf(s1, hv.y, a.y);
    o.z = fmaf(s1, hv.z, a.z);
    o.w = fmaf(s1, hv.w, a.w);
    if (half == 0)
        *(float4*)&hin[((long long)wid << 7) + col4] = o;
}

// ---------------- Weight pre-conversion into MFMA fragment order ----------------
// sigma(kc,g,j) = kc*32 + 8*g + j  -- the SAME bijection used for the A
// operand at runtime, so the MFMA dot-product is correct regardless of the
// hardware's internal (lane,j)->k mapping (A and B maps mirror each other).
// Layout: Wb[(L*4+kc)*8+n][lane][j]  (512 shorts per fragment), hi and lo.
__global__ __launch_bounds__(256) void k_wconv(
    const float* __restrict__ W1, const float* __restrict__ W2,
    unsigned short* __restrict__ WbH, unsigned short* __restrict__ WbL)
{
    int flat = blockIdx.x * 256 + threadIdx.x;   // 4096 threads total
    const float* W = (flat & 2048) ? W2 : W1;
    int kc = (flat >> 9) & 3;
    int n = (flat >> 6) & 7;
    int lane = flat & 63;
    int g = lane >> 4, r = lane & 15;
    int col = n * 16 + r;
#pragma unroll
    for (int j = 0; j < 8; j++) {
        int k = kc * 32 + 8 * g + j;
        float x = W[k * D + col];
        unsigned short hh = f2bf(x);
        WbH[flat * 8 + j] = hh;
        WbL[flat * 8 + j] = f2bf(x - bf2f(hh));
    }
}

// ---------------- Fused 2-layer MLP via split-bf16 MFMA ----------------
// out = prelu_alpha( relu(hin @ W1 + b1) @ W2 + b2 )
// 256 threads = 4 waves, 64 rows/block; wave w owns rows [w*16, w*16+16).
// Per wave per layer: 4 K-chunks x 8 N-tiles x 3 MFMAs (AhBh+AhBl+AlBh).
// Hidden relayout via XOR-swizzled 32KB LDS (conflict-free b128 reads).
__global__ __launch_bounds__(256) void k_mlp_mfma(
    const float* __restrict__ hin,
    const unsigned short* __restrict__ WbH,
    const unsigned short* __restrict__ WbL,
    const float* __restrict__ b1,
    const float* __restrict__ b2,
    const float* __restrict__ alpha,
    float* __restrict__ out, int N)
{
    __shared__ float hid[64][D];

    const int tid = threadIdx.x;
    const int w = tid >> 6;
    const int l = tid & 63;
    const int g = l >> 4;
    const int r15 = l & 15;
    const int row0 = blockIdx.x * 64;
    const int lrowA = w * 16 + r15;                 // A-operand row (local)
    const long long growA = (long long)row0 + lrowA;
    const bool rowok = growA < N;

    float b1c[8], b2c[8];
#pragma unroll
    for (int n = 0; n < 8; n++) {
        b1c[n] = b1[n * 16 + r15];
        b2c[n] = b2[n * 16 + r15];
    }
    const float al = alpha[0];

    f32x4 acc[8];
#pragma unroll
    for (int n = 0; n < 8; n++) acc[n] = (f32x4)(0.f);

    // ---- layer 1: A straight from global hin ----
    for (int kc = 0; kc < 4; kc++) {
        float av[8];
        if (rowok) {
            float4 a0 = *(const float4*)&hin[growA * D + kc * 32 + 8 * g];
            float4 a1 = *(const float4*)&hin[growA * D + kc * 32 + 8 * g + 4];
            av[0] = a0.x; av[1] = a0.y; av[2] = a0.z; av[3] = a0.w;
            av[4] = a1.x; av[5] = a1.y; av[6] = a1.z; av[7] = a1.w;
        } else {
#pragma unroll
            for (int j = 0; j < 8; j++) av[j] = 0.f;
        }
        bf16x8 Ah, Al;
#pragma unroll
        for (int j = 0; j < 8; j++) {
            unsigned short hh = f2bf(av[j]);
            Ah[j] = (short)hh;
            Al[j] = (short)f2bf(av[j] - bf2f(hh));
        }
        const unsigned short* baseH = WbH + (size_t)(kc * 8) * 512 + l * 8;
        const unsigned short* baseL = WbL + (size_t)(kc * 8) * 512 + l * 8;
#pragma unroll
        for (int n = 0; n < 8; n++) {
            bf16x8 Bh = *(const bf16x8*)(baseH + n * 512);
            bf16x8 Bl = *(const bf16x8*)(baseL + n * 512);
            acc[n] = __builtin_amdgcn_mfma_f32_16x16x32_bf16(Ah, Bh, acc[n], 0, 0, 0);
            acc[n] = __builtin_amdgcn_mfma_f32_16x16x32_bf16(Ah, Bl, acc[n], 0, 0, 0);
            acc[n] = __builtin_amdgcn_mfma_f32_16x16x32_bf16(Al, Bh, acc[n], 0, 0, 0);
        }
    }

    // ---- layer-1 epilogue: relu(acc + b1) -> hid (XOR-swizzled) ----
    // D layout: col = n*16 + (l&15), row(local, within wave tile) = 4*g + r.
#pragma unroll
    for (int n = 0; n < 8; n++) {
#pragma unroll
        for (int r = 0; r < 4; r++) {
            int lr = w * 16 + 4 * g + r;
            float v = fmaxf(acc[n][r] + b1c[n], 0.f);
            hid[lr][(n * 16 + r15) ^ ((lr & 7) << 2)] = v;
        }
        acc[n] = (f32x4)(0.f);
    }
    __syncthreads();

    // ---- layer 2: A from hid ----
    {
        const int sh = (r15 & 7) << 2;
        for (int kc = 0; kc < 4; kc++) {
            int c0 = kc * 32 + 8 * g;
            float4 h0 = *(const float4*)&hid[lrowA][c0 ^ sh];
            float4 h1 = *(const float4*)&hid[lrowA][(c0 + 4) ^ sh];
            float av[8];
            av[0] = h0.x; av[1] = h0.y; av[2] = h0.z; av[3] = h0.w;
            av[4] = h1.x; av[5] = h1.y; av[6] = h1.z; av[7] = h1.w;
            bf16x8 Ah, Al;
#pragma unroll
            for (int j = 0; j < 8; j++) {
                unsigned short hh = f2bf(av[j]);
                Ah[j] = (short)hh;
                Al[j] = (short)f2bf(av[j] - bf2f(hh));
            }
            const unsigned short* baseH = WbH + (size_t)((4 + kc) * 8) * 512 + l * 8;
            const unsigned short* baseL = WbL + (size_t)((4 + kc) * 8) * 512 + l * 8;
#pragma unroll
            for (int n = 0; n < 8; n++) {
                bf16x8 Bh = *(const bf16x8*)(baseH + n * 512);
                bf16x8 Bl = *(const bf16x8*)(baseL + n * 512);
                acc[n] = __builtin_amdgcn_mfma_f32_16x16x32_bf16(Ah, Bh, acc[n], 0, 0, 0);
                acc[n] = __builtin_amdgcn_mfma_f32_16x16x32_bf16(Ah, Bl, acc[n], 0, 0, 0);
                acc[n] = __builtin_amdgcn_mfma_f32_16x16x32_bf16(Al, Bh, acc[n], 0, 0, 0);
            }
        }
    }

    // ---- layer-2 epilogue: prelu(acc + b2) -> hid, then coalesced store ----
    // (our wave only overwrites its own rows, whose reads it has completed)
#pragma unroll
    for (int n = 0; n < 8; n++) {
#pragma unroll
        for (int r = 0; r < 4; r++) {
            int lr = w * 16 + 4 * g + r;
            float v = acc[n][r] + b2c[n];
            v = (v >= 0.f) ? v : al * v;
            hid[lr][(n * 16 + r15) ^ ((lr & 7) << 2)] = v;
        }
    }
    __syncthreads();
#pragma unroll
    for (int it = 0; it < 8; it++) {
        int p = it * 256 + tid;
        int lr = p >> 5;
        int cf = (p & 31) * 4;
        long long grow = (long long)row0 + lr;
        if (grow < N) {
            float4 v = *(const float4*)&hid[lr][cf ^ ((lr & 7) << 2)];
            *(float4*)&out[grow * D + cf] = v;
        }
    }
}

// ---------------- Fallback fused MLP (atomic-scatter path) ----------------
__device__ __forceinline__ void mlp_compute(
    const float in_lds[32][D], float Wl[32][D], const float* __restrict__ W,
    int tid, int cg, int rg, float4 acc[4])
{
    acc[0] = make_float4(0.f, 0.f, 0.f, 0.f);
    acc[1] = make_float4(0.f, 0.f, 0.f, 0.f);
    acc[2] = make_float4(0.f, 0.f, 0.f, 0.f);
    acc[3] = make_float4(0.f, 0.f, 0.f, 0.f);

    for (int kc = 0; kc < 4; kc++) {
        __syncthreads();
        for (int i = tid; i < 32 * (D / 4); i += 256) {
            int k = i >> 5;
            int cc = (i & 31) * 4;
            *(float4*)&Wl[k][cc] = *(const float4*)&W[(kc * 32 + k) * D + cc];
        }
        __syncthreads();

        const int kb = kc * 32;
#pragma unroll
        for (int k4 = 0; k4 < 32; k4 += 4) {
            float4 w0 = *(const float4*)&Wl[k4 + 0][cg];
            float4 w1 = *(const float4*)&Wl[k4 + 1][cg];
            float4 w2 = *(const float4*)&Wl[k4 + 2][cg];
            float4 w3 = *(const float4*)&Wl[k4 + 3][cg];
#pragma unroll
            for (int r = 0; r < 4; r++) {
                float4 iv = *(const float4*)&in_lds[rg + r][kb + k4];
                acc[r].x = fmaf(iv.x, w0.x, acc[r].x);
                acc[r].y = fmaf(iv.x, w0.y, acc[r].y);
                acc[r].z = fmaf(iv.x, w0.z, acc[r].z);
                acc[r].w = fmaf(iv.x, w0.w, acc[r].w);
                acc[r].x = fmaf(iv.y, w1.x, acc[r].x);
                acc[r].y = fmaf(iv.y, w1.y, acc[r].y);
                acc[r].z = fmaf(iv.y, w1.z, acc[r].z);
                acc[r].w = fmaf(iv.y, w1.w, acc[r].w);
                acc[r].x = fmaf(iv.z, w2.x, acc[r].x);
                acc[r].y = fmaf(iv.z, w2.y, acc[r].y);
                acc[r].z = fmaf(iv.z, w2.z, acc[r].z);
                acc[r].w = fmaf(iv.z, w2.w, acc[r].w);
                acc[r].x = fmaf(iv.w, w3.x, acc[r].x);
                acc[r].y = fmaf(iv.w, w3.y, acc[r].y);
                acc[r].z = fmaf(iv.w, w3.z, acc[r].z);
                acc[r].w = fmaf(iv.w, w3.w, acc[r].w);
            }
        }
    }
}

__global__ __launch_bounds__(256) void k_mlp2_fb(
    const float* __restrict__ A,
    const float* __restrict__ B,
    const float* __restrict__ W1,
    const float* __restrict__ b1,
    const float* __restrict__ W2,
    const float* __restrict__ b2,
    const float* __restrict__ eps,
    const float* __restrict__ alpha,
    float* __restrict__ out,
    int N)
{
    __shared__ float in_lds[32][D];
    __shared__ float Wl[32][D];

    const int tid = threadIdx.x;
    const int cg = (tid & 31) * 4;
    const int rg = (tid >> 5) * 4;
    const int row0 = blockIdx.x * 32;

    {
        const float s1 = 1.0f + eps[0];
        for (int i = tid; i < 32 * (D / 4); i += 256) {
            int r = i >> 5;
            int cc = (i & 31) * 4;
            float4 v = make_float4(0.f, 0.f, 0.f, 0.f);
            if (row0 + r < N) {
                float4 a = *(const float4*)&A[(long long)(row0 + r) * D + cc];
                float4 b4 = *(const float4*)&B[(long long)(row0 + r) * D + cc];
                v.x = fmaf(s1, a.x, b4.x);
                v.y = fmaf(s1, a.y, b4.y);
                v.z = fmaf(s1, a.z, b4.z);
                v.w = fmaf(s1, a.w, b4.w);
            }
            *(float4*)&in_lds[r][cc] = v;
        }
    }

    float4 acc[4];
    mlp_compute(in_lds, Wl, W1, tid, cg, rg, acc);

    __syncthreads();
    {
        float4 bb = *(const float4*)&b1[cg];
#pragma unroll
        for (int r = 0; r < 4; r++) {
            float4 v;
            v.x = fmaxf(acc[r].x + bb.x, 0.0f);
            v.y = fmaxf(acc[r].y + bb.y, 0.0f);
            v.z = fmaxf(acc[r].z + bb.z, 0.0f);
            v.w = fmaxf(acc[r].w + bb.w, 0.0f);
            *(float4*)&in_lds[rg + r][cg] = v;
        }
    }

    mlp_compute(in_lds, Wl, W2, tid, cg, rg, acc);

    {
        float4 bb = *(const float4*)&b2[cg];
        const float al = alpha[0];
#pragma unroll
        for (int r = 0; r < 4; r++) {
            int row = row0 + rg + r;
            if (row < N) {
                float4 v;
                v.x = acc[r].x + bb.x; v.x = (v.x >= 0.0f) ? v.x : al * v.x;
                v.y = acc[r].y + bb.y; v.y = (v.y >= 0.0f) ? v.y : al * v.y;
                v.z = acc[r].z + bb.z; v.z = (v.z >= 0.0f) ? v.z : al * v.z;
                v.w = acc[r].w + bb.w; v.w = (v.w >= 0.0f) ? v.w : al * v.w;
                *(float4*)&out[(long long)row * D + cg] = v;
            }
        }
    }
}

extern "C" void kernel_launch(void* const* d_in, const int* in_sizes, int n_in,
                              void* d_out, int out_size, void* d_ws, size_t ws_size,
                              hipStream_t stream)
{
    const float* h     = (const float*)d_in[0];
    // d_in[1] = snorm_n (unused by reference)
    const int*   src   = (const int*)d_in[2];
    const int*   dst   = (const int*)d_in[3];
    const float* mask  = (const float*)d_in[4];
    const float* eps   = (const float*)d_in[5];
    const float* W1    = (const float*)d_in[6];
    const float* b1    = (const float*)d_in[7];
    const float* W2    = (const float*)d_in[8];
    const float* b2    = (const float*)d_in[9];
    const float* alpha = (const float*)d_in[10];

    const int N = in_sizes[0] / D;
    const int E = in_sizes[2];
    float* out = (float*)d_out;

    const int NB = (N + 255) / 256;  // scan blocks

    // Workspace layout (256B aligned)
    char* base = (char*)d_ws;
    size_t offHin = 0;
    size_t offEs  = (offHin + (size_t)N * D * 4 + 255) & ~(size_t)255;
    size_t offRp  = (offEs + (size_t)E * 8 + 255) & ~(size_t)255;
    size_t offCnt = (offRp + (size_t)(N + 1) * 4 + 255) & ~(size_t)255;
    size_t offCur = (offCnt + (size_t)N * 4 + 255) & ~(size_t)255;
    size_t offBs  = (offCur + (size_t)N * 4 + 255) & ~(size_t)255;
    size_t offWbH = (offBs + (size_t)NB * 4 + 255) & ~(size_t)255;
    size_t offWbL = (offWbH + 65536 + 255) & ~(size_t)255;
    size_t need   = offWbL + 65536;

    if (ws_size >= need) {
        // ---------- sorted-gather path + MFMA MLP ----------
        float* hin    = (float*)(base + offHin);
        int2*  es     = (int2*)(base + offEs);
        int*   rowptr = (int*)(base + offRp);
        int*   cnt    = (int*)(base + offCnt);
        int*   cursor = (int*)(base + offCur);
        int*   bsum   = (int*)(base + offBs);
        unsigned short* WbH = (unsigned short*)(base + offWbH);
        unsigned short* WbL = (unsigned short*)(base + offWbL);

        hipMemsetAsync(cnt, 0, (size_t)N * 4, stream);
        k_wconv<<<16, 256, 0, stream>>>(W1, W2, WbH, WbL);

        int eblocks = (E + 255) / 256;
        k_hist<<<eblocks, 256, 0, stream>>>(dst, cnt, E);
        k_scanA<<<NB, 256, 0, stream>>>(cnt, rowptr, bsum, N);
        k_scanC2<<<(N + 1 + 255) / 256, 256, 0, stream>>>(rowptr, bsum, cursor,
                                                          N, E, NB);
        k_reorder<<<eblocks, 256, 0, stream>>>(src, dst, mask, cursor, es, E);
        k_gather<<<(N + 3) / 4, 256, 0, stream>>>(h, rowptr, es, eps, hin, N);

        int mblocks64 = (N + 63) / 64;
        k_mlp_mfma<<<mblocks64, 256, 0, stream>>>(hin, WbH, WbL, b1, b2,
                                                  alpha, out, N);
    } else {
        // ---------- fallback: atomic-scatter path ----------
        float* neigh = (float*)d_ws;
        hipMemsetAsync(neigh, 0, (size_t)N * D * sizeof(float), stream);
        long long total = (long long)E * D;
        int blocks = (int)((total + 255) / 256);
        k_scatter<<<blocks, 256, 0, stream>>>(h, src, dst, mask, neigh, total);
        int mblocks = (N + 31) / 32;
        k_mlp2_fb<<<mblocks, 256, 0, stream>>>(h, neigh, W1, b1, W2, b2,
                                               eps, alpha, out, N);
    }
}